// Round 1
// 4028.496 us; speedup vs baseline: 1.0001x; 1.0001x over previous
//
#include <hip/hip_runtime.h>
#include <stdint.h>

// Bidirectional GRU, 6 layers, H=256, S=512, B=10, fp32 in/out, bf16 MFMA.
// 7 live scans (fwd 0..5 + bwd 5). One 512-thread WG per scan; gates staged
// by helper WGs (3 per stream), consumed via global_load_lds (SC1).
// THIS ROUND — kill the helper store-ack serialization:
//   WRITE_SIZE 494MB == 4x sector amplification of 8B agent-scope stores
//   (4096 txns per 32KB slot + in-loop vmcnt(0) ack wait => helper iter
//   ~11us, /3 helpers == measured 3.9us/step). Fix:
//   1) slot publish: 8x AST(u64) -> 4x global_store_dwordx4 sc1 (16B)
//   2) tag publish deferred one helper-iteration (ack overlaps compute;
//      drain->barrier->tag discipline preserved)
//   3) scan h publish: 2x AST(u64) -> 1x 16B sc1 store
// Ordering invariants unchanged: data drained (vmcnt) + all-waves barrier
// before any tag store; tags are the only sub-16B device-scope stores left.

typedef short short8 __attribute__((ext_vector_type(8)));
typedef float floatx4 __attribute__((ext_vector_type(4)));
typedef unsigned long long u64;
typedef unsigned int u32;
typedef unsigned short u16;

#define SEQ 512

// ws: gring 7*32 slots x 32KB (rz bf16 [512][16] + nx f32 [256][16]) = 7.34MB
//     hh   scans 0..4 [t:512][b:16][ch:128] bf16 = 10.5MB
//     tags u32: gtag[7][32] @0 ; htag[5][512] @256 ; cparr[7] @2816
#define GSLOT_U64 4096
#define GRING_U64 (7 * 32 * GSLOT_U64)
#define HH_U16 (5 * 512 * 2048)
#define TAGS_OFF_B ((size_t)GRING_U64 * 8 + (size_t)HH_U16 * 2)

__device__ __forceinline__ u16 f2bf(float f){ union{float f;u32 i;}v; v.f=f; u32 u=v.i; u += 0x7fffu + ((u>>16)&1u); return (u16)(u>>16); }
__device__ __forceinline__ float bf2f(u16 h){ union{u32 i;float f;}v; v.i=((u32)h)<<16; return v.f; }
__device__ __forceinline__ short8 ld8f(const float* p){
    float4 a=*(const float4*)p, b=*(const float4*)(p+4);
    short8 r; r[0]=(short)f2bf(a.x); r[1]=(short)f2bf(a.y); r[2]=(short)f2bf(a.z); r[3]=(short)f2bf(a.w);
    r[4]=(short)f2bf(b.x); r[5]=(short)f2bf(b.y); r[6]=(short)f2bf(b.z); r[7]=(short)f2bf(b.w); return r;
}
__device__ __forceinline__ short8 pk2(u64 a, u64 b){ union{u64 q[2]; short8 s;}v; v.q[0]=a; v.q[1]=b; return v.s; }
__device__ __forceinline__ u64 pack4bf(floatx4 a){
    return (u64)f2bf(a[0]) | ((u64)f2bf(a[1])<<16) | ((u64)f2bf(a[2])<<32) | ((u64)f2bf(a[3])<<48);
}
__device__ __forceinline__ float sigmoidf_(float x){ return 1.0f/(1.0f+__expf(-x)); }
__device__ __forceinline__ float tanhf_(float x){ float e=__expf(2.0f*x); return 1.0f-2.0f/(e+1.0f); }

#define ALD(p)    __hip_atomic_load((p), __ATOMIC_RELAXED, __HIP_MEMORY_SCOPE_AGENT)
#define AST(p,v)  __hip_atomic_store((p),(v),__ATOMIC_RELAXED,__HIP_MEMORY_SCOPE_AGENT)
__device__ __forceinline__ void wait_vm0(){ asm volatile("s_waitcnt vmcnt(0)" ::: "memory"); }
__device__ __forceinline__ void wait_vm4(){ asm volatile("s_waitcnt vmcnt(4)" ::: "memory"); }
__device__ __forceinline__ void lgkm_barrier(){ asm volatile("s_waitcnt lgkmcnt(0)\n\ts_barrier" ::: "memory"); }

// 16B device-scope (MALL-visible) store: sc1 == the cache-policy bit
// __hip_atomic_store(AGENT) compiles to, but at dwordx4 width.
__device__ __forceinline__ void st16_sc1(void* p, floatx4 v){
    asm volatile("global_store_dwordx4 %0, %1, off sc1" :: "v"(p), "v"(v) : "memory");
}

// global->LDS DMA, 16B/lane, aux=16 (SC1: device-scope, bypass per-XCD L2)
__device__ __forceinline__ void dma16(const void* g, void* l) {
    __builtin_amdgcn_global_load_lds(
        reinterpret_cast<const __attribute__((address_space(1))) unsigned int*>(
            (uintptr_t)g),
        reinterpret_cast<__attribute__((address_space(3))) unsigned int*>(
            (uintptr_t)l), 16, 0, 16);
}

__global__ __launch_bounds__(512, 2)
void gru_pipeline(const float* __restrict__ x,
                  const float* __restrict__ wihl0,
                  const float* __restrict__ wihrest,
                  const float* __restrict__ whh,
                  float* __restrict__ out,
                  u64* __restrict__ gring,
                  u16* __restrict__ hhb,
                  u32* __restrict__ tags)
{
    __shared__ u64 smem_[14400];   // 115,200 B: gbuf 3x32768 + hbuf 16,896 (=> 1 block/CU)
    const int blk  = blockIdx.x;
    const int tid  = threadIdx.x;
    const int w    = tid >> 6;
    const int lane = tid & 63;
    const int n16  = lane & 15;
    const int quad = lane >> 4;
    u32* cparr = tags + 2816;

    if (blk < 7) {
        // ================= SCAN: one 512-thread WG per scan =================
        const int s = blk;
        const int layer = (s==6)?5:s, dir=(s==6)?1:0;
        const float* whhp = whh + ((size_t)(layer*2+dir))*768*256;

        // W_hh B-frags: wave owns units j in [32w,32w+32): tiles m=g*2+u
        short8 bh[6][8];
#pragma unroll
        for (int g=0; g<3; ++g)
#pragma unroll
        for (int u=0; u<2; ++u) {
            const int row = g*256 + 32*w + 16*u + n16;
#pragma unroll
            for (int q=0; q<8; ++q)
                bh[g*2+u][q] = ld8f(whhp + (size_t)row*256 + q*32 + quad*8);
        }

        char* gb   = (char*)smem_;            // gate slots: [3][32768 B]
        u16*  hbuf = (u16*)(gb + 98304);      // [2][16][264] bf16
        for (int i=tid; i<8448; i+=512) hbuf[i] = 0;   // h(-1)=0 (both slots)

        u32* gtp = tags + s*32;
        u32* htp = tags + 256 + s*512;

        // prologue: stage gates(0) and gates(1)
        {
            int gd=0;
            while (ALD(gtp + 0) != 1u){ if(++gd>3000000) break; __builtin_amdgcn_s_sleep(2); }
            const char* sg = (const char*)(gring + (size_t)(s*32)*GSLOT_U64);
#pragma unroll
            for (int r=0; r<4; ++r) dma16(sg + (r*512+tid)*16, gb + (r*512+tid)*16);
            gd=0;
            while (ALD(gtp + 1) != 2u){ if(++gd>3000000) break; __builtin_amdgcn_s_sleep(2); }
            sg = (const char*)(gring + (size_t)(s*32 + 1)*GSLOT_U64);
#pragma unroll
            for (int r=0; r<4; ++r) dma16(sg + (r*512+tid)*16, gb + 32768 + (r*512+tid)*16);
            wait_vm0(); lgkm_barrier();
        }

        for (int t=0; t<SEQ; ++t) {
            // A: tags. h(t-2) data drained by end of step t-1 (vmcnt partial).
            if (tid==0) {
                AST(cparr + s, (u32)(t+1));
                if (s<=4 && t>=2) AST(htp + (t-2), (u32)(t-1));
            }
            // early poll of gtag(t+2); value consumed at phase F
            const bool need2 = (t+2 < SEQ);
            u32 tg2 = 0;
            if (need2) tg2 = ALD(gtp + ((t+2)&31));

            // B: publish h(t-1) / out(t-1) from LDS slot t&1
            const u16* hbP = hbuf + (t&1)*4224;
            if (t >= 1) {
                if (s<=4) {
                    if (tid < 256) {        // b = tid&15, 16B chunk k = tid>>4
                        const int b = tid & 15, k = tid >> 4;
                        char* hq = (char*)(hhb + (size_t)s*1048576 + (size_t)(t-1)*2048);
                        st16_sc1(hq + b*256 + k*16, *(const floatx4*)(hbP + b*264 + 8*k));
                    }
                } else {
                    const int off = (s==6)?256:0;
#pragma unroll
                    for (int k=0;k<5;++k) {
                        const int idx = tid + 512*k, b = idx >> 8, j = idx & 255;
                        if (b < 10)
                            out[(size_t)(t-1)*5120 + (size_t)b*512 + off + j] = bf2f(hbP[b*264 + j]);
                    }
                }
            }
            // D: acc init (r,z x-parts from slot t%3) + 48 MFMAs over K=256
            const char* g0 = gb + (t%3)*32768;
            floatx4 acc[6];
#pragma unroll
            for (int g=0; g<2; ++g)
#pragma unroll
            for (int u=0; u<2; ++u) {
                const int col = g*256 + 32*w + 16*u + n16;
                const u64 gw = *(const u64*)(g0 + col*32 + quad*8);
#pragma unroll
                for (int r=0; r<4; ++r) acc[g*2+u][r] = bf2f((u16)(gw >> (16*r)));
            }
            acc[4] = (floatx4){0.f,0.f,0.f,0.f};
            acc[5] = (floatx4){0.f,0.f,0.f,0.f};
#pragma unroll
            for (int q=0; q<8; ++q) {
                short8 ah = *(const short8*)(hbP + n16*264 + q*32 + quad*8);
#pragma unroll
                for (int m=0; m<6; ++m)
                    acc[m] = __builtin_amdgcn_mfma_f32_16x16x32_bf16(ah, bh[m][q], acc[m], 0,0,0);
            }
            // E: nonlinearity, h(t) -> LDS slot (t+1)&1
            u16* hbN = hbuf + ((t+1)&1)*4224;
            const float* nxp = (const float*)(g0 + 16384);
#pragma unroll
            for (int u=0; u<2; ++u) {
                const int j = 32*w + 16*u + n16;
                const floatx4 nx4 = *(const floatx4*)(nxp + j*16 + quad*4);
#pragma unroll
                for (int r=0; r<4; ++r) {
                    const int b = quad*4 + r;
                    float rr = sigmoidf_(acc[u][r]);
                    float zz = sigmoidf_(acc[2+u][r]);
                    float nn = tanhf_(nx4[r] + rr*acc[4+u][r]);
                    float hp = bf2f(hbP[b*264 + j]);
                    float hn = (1.0f-zz)*nn + zz*hp;
                    hbN[b*264 + j] = f2bf(hn);
                }
            }
            // F: issue DMA gates(t+2) -> slot (t+2)%3, then partial drain:
            // vmcnt(4) leaves ONLY the 4 fresh DMAs in flight; all older ops
            // (h/out stores, DMA(t+1)) complete before the barrier.
            if (need2) {
                if (tg2 != (u32)(t+3)) {
                    int gd=0;
                    while (ALD(gtp + ((t+2)&31)) != (u32)(t+3)){ if(++gd>3000000) break; __builtin_amdgcn_s_sleep(1); }
                }
                const char* sg = (const char*)(gring + (size_t)(s*32 + ((t+2)&31))*GSLOT_U64);
                char* dg = gb + ((t+2)%3)*32768;
#pragma unroll
                for (int r=0; r<4; ++r) dma16(sg + (r*512+tid)*16, dg + (r*512+tid)*16);
                wait_vm4();
            } else {
                wait_vm0();
            }
            lgkm_barrier();
        }
        // epilogue: h(511)/out(511) live in slot (512&1)=0
        const u16* hbL = hbuf;
        if (s<=4) {
            if (tid < 256) {
                const int b = tid & 15, k = tid >> 4;
                char* hq = (char*)(hhb + (size_t)s*1048576 + (size_t)(SEQ-1)*2048);
                st16_sc1(hq + b*256 + k*16, *(const floatx4*)(hbL + b*264 + 8*k));
            }
        } else {
            const int off = (s==6)?256:0;
#pragma unroll
            for (int k=0;k<5;++k) {
                const int idx = tid + 512*k, b = idx >> 8, j = idx & 255;
                if (b < 10)
                    out[(size_t)(SEQ-1)*5120 + (size_t)b*512 + off + j] = bf2f(hbL[b*264 + j]);
            }
        }
        wait_vm0(); lgkm_barrier();
        if (tid==0 && s<=4) { AST(htp + 510, 511u); AST(htp + 511, 512u); }
        return;
    }

    // ================= HELPERS: gates_x producers (3 WGs/stream) =================
    int sh, t0;
    if (blk < 10)      { sh = 0;               t0 = blk - 7;      }
    else if (blk < 25) { sh = 1 + (blk-10)/3;  t0 = (blk-10)%3;   }
    else               { sh = 6;               t0 = blk - 25;     }

    const int layer = (sh==6)?5:sh, dir=(sh==6)?1:0;
    const float* wihp; int stride;
    if (layer==0){ wihp = wihl0 + (size_t)dir*768*128; stride=128; }
    else         { wihp = wihrest + ((size_t)((layer-1)*2+dir))*768*512; stride=512; }

    // 8 waves x 6 tiles: gate col = (w*6+i)*16 + n16
    short8 bxf[6][4];
#pragma unroll
    for (int i=0; i<6; ++i) {
        const int col = (w*6+i)*16 + n16;
#pragma unroll
        for (int q=0; q<4; ++q)
            bxf[i][q] = ld8f(wihp + (size_t)col*stride + q*32 + quad*8);
    }
    char* tb = (char*)smem_;               // 32 KB slot image
    const int bmA = (n16>9)?9:n16;
    const int lsrc = (sh==6)? 4 : (sh-1);
    u32* gtp_sh = tags + sh*32;

    // Software-pipelined publish: slot t's 16B sc1 stores are issued at
    // iteration t; its tag is published at iteration t+3 after wait_vm0 +
    // barrier (store-ack overlaps the next slot's load+MFMA). Margin: tag(t)
    // needs only cparr >= t-21 to publish, consumer blocks on it at step t-2.
    int tprev = -1;
    for (int t = t0; t < SEQ; t += 3) {
        if (t >= 32) {   // ring-32 flow control vs consumer scan (lead <= 24)
            int gd=0;
            while ((int)ALD(cparr + sh) < t-24){ if(++gd>1000000) break; __builtin_amdgcn_s_sleep(8); }
        }
        if (tprev >= 0) {
            wait_vm0();            // own wave's slot-(tprev) stores acked
            __syncthreads();       // all waves acked (+ all tb readers done)
            if (tid==0) AST(gtp_sh + (tprev&31), (u32)(tprev+1));
        }
        short8 ax[4];
        if (sh == 0) {
            const float* xr = x + (size_t)t*1280 + (size_t)bmA*128;
#pragma unroll
            for (int q=0; q<4; ++q) ax[q] = ld8f(xr + q*32 + quad*8);
        } else {
            const int srct = (sh==6)? (SEQ-1-t) : t;
            int gd=0;
            while (ALD(tags + 256 + lsrc*512 + srct) != (u32)(srct+1)){ if(++gd>3000000) break; __builtin_amdgcn_s_sleep(4); }
            const u64* hq = (const u64*)(hhb + (size_t)lsrc*1048576 + (size_t)srct*2048);
#pragma unroll
            for (int q=0; q<4; ++q) {
                u64 a = ALD(hq + n16*32 + q*8 + quad*2);
                u64 b = ALD(hq + n16*32 + q*8 + quad*2 + 1);
                ax[q] = pk2(a, b);
            }
        }
        floatx4 acc[6];
#pragma unroll
        for (int i=0; i<6; ++i) acc[i] = (floatx4){0.f,0.f,0.f,0.f};
#pragma unroll
        for (int q=0; q<4; ++q)
#pragma unroll
            for (int i=0; i<6; ++i)
                acc[i] = __builtin_amdgcn_mfma_f32_16x16x32_bf16(ax[q], bxf[i][q], acc[i], 0,0,0);

        // slot image in LDS: rz bf16 [col<512][16], nx f32 [col-512][16]
        // (tb overwrite is safe: the tag barrier above drained all readers)
#pragma unroll
        for (int i=0; i<6; ++i) {
            const int col = (w*6+i)*16 + n16;
            if (col < 512) *(u64*)(tb + col*32 + quad*8) = pack4bf(acc[i]);
            else           *(floatx4*)(tb + 16384 + (col-512)*64 + quad*16) = acc[i];
        }
        __syncthreads();
        // publish 32KB slot: 4x 16B sc1 stores per thread (was 8x 8B AST ->
        // 4096 txns + in-loop full ack wait = the old 11us helper iteration)
        char* gq = (char*)(gring + (size_t)(sh*32 + (t&31))*GSLOT_U64);
#pragma unroll
        for (int k=0;k<4;++k)
            st16_sc1(gq + tid*64 + k*16, *(const floatx4*)((const char*)tb + tid*64 + k*16));
        tprev = t;
    }
    wait_vm0(); __syncthreads();
    if (tid==0 && tprev>=0) AST(gtp_sh + (tprev&31), (u32)(tprev+1));
}

extern "C" void kernel_launch(void* const* d_in, const int* in_sizes, int n_in,
                              void* d_out, int out_size, void* d_ws, size_t ws_size,
                              hipStream_t stream) {
    (void)in_sizes; (void)n_in; (void)out_size; (void)ws_size;
    const float* x       = (const float*)d_in[0];
    const float* wihl0   = (const float*)d_in[1];
    const float* wihrest = (const float*)d_in[2];
    const float* whh     = (const float*)d_in[3];
    float* out = (float*)d_out;
    u64* gring = (u64*)d_ws;
    u16* hhb   = (u16*)((char*)d_ws + (size_t)GRING_U64*8);
    u32* tags  = (u32*)((char*)d_ws + TAGS_OFF_B);

    // No memset: 0xAAAAAAAA poison never equals a valid tag (1..512);
    // flow-control reads cast to int (poison negative => "not yet").
    gru_pipeline<<<dim3(28), dim3(512), 0, stream>>>(x, wihl0, wihrest, whh, out,
                                                     gring, hhb, tags);
}